// Round 9
// baseline (59.971 us; speedup 1.0000x reference)
//
#include <hip/hip_runtime.h>

typedef float f4 __attribute__((ext_vector_type(4)));

// Helper: one wave (64 threads) per segment. Block b computes
// start_b = sum(dia_len[0..b)) via strided per-lane sums + wave reduce,
// then writes pos[start_b + k] = k for k in [0, len_b).
__global__ void __launch_bounds__(64)
pe_pos_kernel(const int* __restrict__ dia_len, int n_seg,
              int* __restrict__ pos) {
    const int b = blockIdx.x;           // segment id
    const int t = threadIdx.x;          // lane
    int partial = 0;
    for (int j = t; j < b; j += 64) partial += dia_len[j];
    #pragma unroll
    for (int off = 32; off > 0; off >>= 1)
        partial += __shfl_down(partial, off, 64);
    const int start = __shfl(partial, 0, 64);
    const int len = dia_len[b];
    for (int k = t; k < len; k += 64) pos[start + k] = k;
}

// Main: position-class traversal. Block (r0 = bid&63, chk = bid>>6)
// handles rows r0 + 64*m for m in [chk*16, chk*16+16). When segment
// lengths are uniform-64 (this input), all 16 rows share pos == r0, so
// the block's pe row (4 KB, one f4 per thread) is loaded ONCE and held
// in a register -> pe fabric traffic drops 134 MB -> ~8 MB. General
// dia_len stays correct: pos[row] is re-checked per row and pe reloaded
// on change. x/out remain fully coalesced (wave reads contiguous 1 KB).
__global__ void __launch_bounds__(256)
pe_add_kernel(const f4* __restrict__ x,
              const f4* __restrict__ pe,
              const int* __restrict__ pos,
              f4* __restrict__ out, int n_rows) {
    const int c   = threadIdx.x;        // f4 column 0..255 (D=1024 floats)
    const int r0  = blockIdx.x & 63;    // position-class start row
    const int chk = blockIdx.x >> 6;    // 0..31: which run of 16 rows

    int p_cur = -1;
    f4 pv;
    #pragma unroll 4
    for (int j = 0; j < 16; ++j) {
        const int m = chk * 16 + j;             // 0..511
        const int row = r0 + (m << 6);          // r0 + 64*m
        if (row < n_rows) {
            const int p = pos[row];             // wave-uniform broadcast
            if (p != p_cur) {                   // uniform branch; 1x per block
                p_cur = p;                      //   for uniform-64 input
                pv = pe[((long)p << 8) | c];
            }
            const long i = ((long)row << 8) | c;
            const f4 a = x[i];
            __builtin_nontemporal_store(a + pv, &out[i]);
        }
    }
}

extern "C" void kernel_launch(void* const* d_in, const int* in_sizes, int n_in,
                              void* d_out, int out_size, void* d_ws, size_t ws_size,
                              hipStream_t stream) {
    const float* x  = (const float*)d_in[0];
    const float* pe = (const float*)d_in[1];
    const int*   dl = (const int*)d_in[2];

    const int n_seg  = in_sizes[2];          // 512
    const int n_rows = out_size / 1024;      // 32768 rows (D_MODEL = 1024)
    int* pos = (int*)d_ws;                   // n_rows * 4 B = 128 KB

    pe_pos_kernel<<<n_seg, 64, 0, stream>>>(dl, n_seg, pos);

    // 64 position-classes x 32 chunks = 2048 blocks x 256 thr
    // = 8192 waves = 32 waves/CU (full TLP).
    pe_add_kernel<<<2048, 256, 0, stream>>>(
        (const f4*)x, (const f4*)pe, pos, (f4*)d_out, n_rows);
}

// Round 10
// 47.596 us; speedup vs baseline: 1.2600x; 1.2600x over previous
//
#include <hip/hip_runtime.h>

typedef float f4 __attribute__((ext_vector_type(4)));

// out[row][c] = x[row][c] + pe[row - seg_start(row)][c]
// R5 streaming layout (proven best x/out pattern) + pe-in-register:
// stride = 524288 f4 = 2048 rows, so per thread (i & 255) is constant
// and row mod 2048 is constant -> position-within-segment is constant
// for uniform-64 segments. pe operand = ONE f4 register, reloaded only
// when pos changes (general dia_len stays correct).
__global__ void __launch_bounds__(512)
pe_fused_kernel(const f4* __restrict__ x,
                const f4* __restrict__ pe,
                const int* __restrict__ dia_len, int n_seg,
                f4* __restrict__ out, long n4) {
    __shared__ int ex[513];      // exclusive cumsum; seg s = rows [ex[s], ex[s+1])
    __shared__ int seg_lo[512];  // segment containing row b*64 (also scan scratch)
    const int t = threadIdx.x;

    seg_lo[t] = (t < n_seg) ? dia_len[t] : 0;
    __syncthreads();
    #pragma unroll
    for (int off = 1; off < 512; off <<= 1) {
        int add = (t >= off) ? seg_lo[t - off] : 0;
        __syncthreads();
        seg_lo[t] += add;
        __syncthreads();
    }
    ex[t + 1] = seg_lo[t];
    if (t == 0) ex[0] = 0;
    __syncthreads();
    if (t < n_seg) {
        const int st = ex[t], en = ex[t + 1];
        for (int b = (st + 63) >> 6; (b << 6) < en; ++b) seg_lo[b] = t;
    }
    __syncthreads();

    const long stride = (long)gridDim.x * blockDim.x;
    long i = (long)blockIdx.x * blockDim.x + threadIdx.x;
    const int col = (int)(i & 255);   // constant per thread (stride % 256 == 0)

    #define PE_POS(ROW, P)                                            \
        int P;                                                        \
        {                                                             \
            int s_ = seg_lo[(ROW) >> 6];                              \
            while (ex[s_ + 1] <= (ROW)) ++s_;                         \
            P = (ROW) - ex[s_];                                       \
        }

    // Register-cached pe value; reload only when position changes.
    int p_cur = -1;
    f4 pv;
    #define PE_GET(P, B)                                              \
        if ((P) != p_cur) { p_cur = (P); pv = pe[((long)p_cur << 8) | col]; } \
        const f4 B = pv;

    for (; i + 3 * stride < n4; i += 4 * stride) {
        const long i0 = i, i1 = i + stride, i2 = i + 2 * stride, i3 = i + 3 * stride;
        // batch the 4 x loads first (independent, in flight together)
        const f4 a0 = x[i0], a1 = x[i1], a2 = x[i2], a3 = x[i3];
        const int r0 = (int)(i0 >> 8), r1 = (int)(i1 >> 8),
                  r2 = (int)(i2 >> 8), r3 = (int)(i3 >> 8);
        PE_POS(r0, p0) PE_POS(r1, p1) PE_POS(r2, p2) PE_POS(r3, p3)
        PE_GET(p0, b0)
        __builtin_nontemporal_store(a0 + b0, &out[i0]);
        PE_GET(p1, b1)
        __builtin_nontemporal_store(a1 + b1, &out[i1]);
        PE_GET(p2, b2)
        __builtin_nontemporal_store(a2 + b2, &out[i2]);
        PE_GET(p3, b3)
        __builtin_nontemporal_store(a3 + b3, &out[i3]);
    }
    for (; i < n4; i += stride) {
        const int row = (int)(i >> 8);
        PE_POS(row, p)
        PE_GET(p, b)
        const f4 a = x[i];
        __builtin_nontemporal_store(a + b, &out[i]);
    }
    #undef PE_POS
    #undef PE_GET
}

extern "C" void kernel_launch(void* const* d_in, const int* in_sizes, int n_in,
                              void* d_out, int out_size, void* d_ws, size_t ws_size,
                              hipStream_t stream) {
    const float* x  = (const float*)d_in[0];
    const float* pe = (const float*)d_in[1];
    const int*   dl = (const int*)d_in[2];

    const int n_seg = in_sizes[2];           // 512 (<= 512 for LDS tables)
    const long n4 = (long)out_size / 4;      // 8,388,608 f4 -> 16 per thread

    pe_fused_kernel<<<1024, 512, 0, stream>>>(
        (const f4*)x, (const f4*)pe, dl, n_seg, (f4*)d_out, n4);
}

// Round 11
// 46.339 us; speedup vs baseline: 1.2942x; 1.0271x over previous
//
#include <hip/hip_runtime.h>

typedef float f4 __attribute__((ext_vector_type(4)));

// out[row][c] = x[row][c] + pe[row - seg_start(row)][c]
// R10 body (grid-stride streaming + pe-in-register + nt-stores) with a
// cheap prologue: wave-level shfl scan (3 barriers) instead of the
// 512-wide Hillis-Steele (19 barriers).
__global__ void __launch_bounds__(512)
pe_fused_kernel(const f4* __restrict__ x,
                const f4* __restrict__ pe,
                const int* __restrict__ dia_len, int n_seg,
                f4* __restrict__ out, long n4) {
    __shared__ int ex[513];      // exclusive cumsum; seg s = rows [ex[s], ex[s+1])
    __shared__ int seg_lo[512];  // bucket b -> segment containing row b*64
    __shared__ int wsum[8];      // per-wave totals
    const int t    = threadIdx.x;
    const int lane = t & 63;
    const int wid  = t >> 6;

    // --- prologue: cumsum of dia_len via wave shuffle scan ---
    const int v = (t < n_seg) ? dia_len[t] : 0;
    int scan = v;
    #pragma unroll
    for (int off = 1; off < 64; off <<= 1) {
        const int u = __shfl_up(scan, off, 64);
        if (lane >= off) scan += u;
    }
    if (lane == 63) wsum[wid] = scan;
    __syncthreads();
    int pre = 0;
    #pragma unroll
    for (int w = 0; w < 8; ++w) pre += (w < wid) ? wsum[w] : 0;
    ex[t + 1] = scan + pre;
    if (t == 0) ex[0] = 0;
    __syncthreads();
    if (t < n_seg) {
        const int st = ex[t], en = ex[t + 1];
        for (int b = (st + 63) >> 6; (b << 6) < en; ++b) seg_lo[b] = t;
    }
    __syncthreads();

    const long stride = (long)gridDim.x * blockDim.x;
    long i = (long)blockIdx.x * blockDim.x + threadIdx.x;
    const int col = (int)(i & 255);   // constant per thread (stride % 256 == 0)

    #define PE_POS(ROW, P)                                            \
        int P;                                                        \
        {                                                             \
            int s_ = seg_lo[(ROW) >> 6];                              \
            while (ex[s_ + 1] <= (ROW)) ++s_;                         \
            P = (ROW) - ex[s_];                                       \
        }

    // Register-cached pe value; reload only when position changes.
    int p_cur = -1;
    f4 pv;
    #define PE_GET(P, B)                                              \
        if ((P) != p_cur) { p_cur = (P); pv = pe[((long)p_cur << 8) | col]; } \
        const f4 B = pv;

    for (; i + 3 * stride < n4; i += 4 * stride) {
        const long i0 = i, i1 = i + stride, i2 = i + 2 * stride, i3 = i + 3 * stride;
        const f4 a0 = x[i0], a1 = x[i1], a2 = x[i2], a3 = x[i3];
        const int r0 = (int)(i0 >> 8), r1 = (int)(i1 >> 8),
                  r2 = (int)(i2 >> 8), r3 = (int)(i3 >> 8);
        PE_POS(r0, p0) PE_POS(r1, p1) PE_POS(r2, p2) PE_POS(r3, p3)
        PE_GET(p0, b0)
        __builtin_nontemporal_store(a0 + b0, &out[i0]);
        PE_GET(p1, b1)
        __builtin_nontemporal_store(a1 + b1, &out[i1]);
        PE_GET(p2, b2)
        __builtin_nontemporal_store(a2 + b2, &out[i2]);
        PE_GET(p3, b3)
        __builtin_nontemporal_store(a3 + b3, &out[i3]);
    }
    for (; i < n4; i += stride) {
        const int row = (int)(i >> 8);
        PE_POS(row, p)
        PE_GET(p, b)
        const f4 a = x[i];
        __builtin_nontemporal_store(a + b, &out[i]);
    }
    #undef PE_POS
    #undef PE_GET
}

extern "C" void kernel_launch(void* const* d_in, const int* in_sizes, int n_in,
                              void* d_out, int out_size, void* d_ws, size_t ws_size,
                              hipStream_t stream) {
    const float* x  = (const float*)d_in[0];
    const float* pe = (const float*)d_in[1];
    const int*   dl = (const int*)d_in[2];

    const int n_seg = in_sizes[2];           // 512 (<= 512 for LDS tables)
    const long n4 = (long)out_size / 4;      // 8,388,608 f4 -> 16 per thread

    pe_fused_kernel<<<1024, 512, 0, stream>>>(
        (const f4*)x, (const f4*)pe, dl, n_seg, (f4*)d_out, n4);
}